// Round 2
// baseline (225.062 us; speedup 1.0000x reference)
//
#include <hip/hip_runtime.h>

#define D 1536
#define BM 128
#define BN 128
#define BK 32
#define TT 64

typedef unsigned short u16;
typedef short bf16x8 __attribute__((ext_vector_type(8)));
typedef short short2v __attribute__((ext_vector_type(2)));
typedef float f32x4 __attribute__((ext_vector_type(4)));

static __device__ __forceinline__ float bf2f(u16 s) {
    unsigned u = ((unsigned)s) << 16;
    float f; __builtin_memcpy(&f, &u, 4); return f;
}
static __device__ __forceinline__ u16 f2bf(float f) {
    unsigned u; __builtin_memcpy(&u, &f, 4);
    unsigned r = (u + 0x7FFFu + ((u >> 16) & 1u)) >> 16;
    return (u16)r;
}

// split packed bf16 x8 into positive part and negative part (sign-mask trick)
static __device__ __forceinline__ void splitpn(bf16x8 a, bf16x8& p, bf16x8& n) {
    union U { bf16x8 v; short2v s[4]; unsigned u[4]; } x, up, un;
    x.v = a;
#pragma unroll
    for (int i = 0; i < 4; ++i) {
        short2v m = x.s[i] >> 15;          // v_pk_ashrrev_i16: 0xFFFF where sign set
        unsigned mu; __builtin_memcpy(&mu, &m, 4);
        unsigned ng = x.u[i] & mu;         // keep where negative
        un.u[i] = ng;
        up.u[i] = x.u[i] ^ ng;             // keep where non-negative
    }
    p = up.v; n = un.v;
}

#define GLDS(g, s) __builtin_amdgcn_global_load_lds( \
    (const __attribute__((address_space(1))) void*)(g), \
    (__attribute__((address_space(3))) void*)(s), 16, 0, 0)

// ---------------- transpose+convert: dst_bf16[m][k] = src_f32[k][m], 6 matrices ----------------
__global__ __launch_bounds__(256) void transpose_k(
    const float* __restrict__ lcs, const float* __restrict__ ucs,
    u16* __restrict__ lcsT, u16* __restrict__ ucsT)
{
    __shared__ u16 t[TT][TT + 8];
    const int z = blockIdx.z, j = z >> 1, sel = z & 1;
    const float* src = (sel ? ucs : lcs) + (size_t)j * D * D;
    u16* dst = (sel ? ucsT : lcsT) + (size_t)j * D * D;
    const int r0 = blockIdx.y * TT, c0 = blockIdx.x * TT;
    const int tid = threadIdx.x;
#pragma unroll
    for (int i = 0; i < 2; ++i) {
        int c = tid + i * 256; int r = c >> 3, v = c & 7;
        const float* p = src + (size_t)(r0 + r) * D + c0 + v * 8;
        f32x4 x0 = *(const f32x4*)p;
        f32x4 x1 = *(const f32x4*)(p + 4);
        bf16x8 y;
#pragma unroll
        for (int e = 0; e < 4; ++e) { y[e] = (short)f2bf(x0[e]); y[e + 4] = (short)f2bf(x1[e]); }
        *(bf16x8*)&t[r][v * 8] = y;
    }
    __syncthreads();
#pragma unroll
    for (int i = 0; i < 2; ++i) {
        int c = tid + i * 256; int rr = c >> 3, v = c & 7;
        bf16x8 x;
#pragma unroll
        for (int e = 0; e < 8; ++e) x[e] = (short)t[v * 8 + e][rr];
        *(bf16x8*)(dst + (size_t)(c0 + rr) * D + r0 + v * 8) = x;
    }
}

// ---------------- convert f32 -> bf16 (layer-3 constraint matrices) ----------------
__global__ __launch_bounds__(256) void convert_k(
    const float* __restrict__ src0, u16* __restrict__ dst0,
    const float* __restrict__ src1, u16* __restrict__ dst1)
{
    const float* src = blockIdx.y ? src1 : src0;
    u16* dst = blockIdx.y ? dst1 : dst0;
    size_t i = ((size_t)blockIdx.x * 256 + threadIdx.x) * 8;
    f32x4 x0 = *(const f32x4*)(src + i);
    f32x4 x1 = *(const f32x4*)(src + i + 4);
    bf16x8 y;
#pragma unroll
    for (int e = 0; e < 4; ++e) { y[e] = (short)f2bf(x0[e]); y[e + 4] = (short)f2bf(x1[e]); }
    *(bf16x8*)(dst + i) = y;
}

// ---------------- init bias accumulators (f32) from layer-3 biases ----------------
__global__ __launch_bounds__(256) void initbias_k(
    const float* __restrict__ ucb3, const float* __restrict__ lcb3,
    float* __restrict__ cb_uc, float* __restrict__ cb_lc)
{
    int i = blockIdx.x * 256 + threadIdx.x;
    if (i < D)          cb_uc[i] = ucb3[i];
    else if (i < 2 * D) cb_lc[i - D] = lcb3[i - D];
}

// ---------------- layer-0 forward bounds: one wave per output row (all f32) ----------------
__global__ __launch_bounds__(256) void lb0ub0_k(
    const float* __restrict__ lb, const float* __restrict__ ub,
    const float* __restrict__ lcs0, const float* __restrict__ ucs0,
    const float* __restrict__ lcb0, const float* __restrict__ ucb0,
    float* __restrict__ lb0, float* __restrict__ ub0)
{
    const int gw = blockIdx.x * 4 + (threadIdx.x >> 6);
    const int lane = threadIdx.x & 63;
    const int which = gw >= D;          // 0: lb0 row, 1: ub0 row
    const int n = which ? gw - D : gw;
    const float* row = (which ? ucs0 : lcs0) + (size_t)n * D;
    const float* vp = which ? ub : lb;
    const float* vn = which ? lb : ub;
    float s = 0.f;
    for (int c2 = 0; c2 < D / 256; ++c2) {
        int base = (c2 * 64 + lane) * 4;
        f32x4 g = *(const f32x4*)(row + base);
        f32x4 p = *(const f32x4*)(vp + base);
        f32x4 m = *(const f32x4*)(vn + base);
#pragma unroll
        for (int e = 0; e < 4; ++e) s += g[e] * (g[e] > 0.f ? p[e] : m[e]);
    }
#pragma unroll
    for (int o = 32; o; o >>= 1) s += __shfl_down(s, o);
    if (lane == 0) {
        float b = which ? ucb0[n] : lcb0[n];
        (which ? ub0 : lb0)[n] = s + b;
    }
}

// ---------------- bias recurrence: cb += bias_j-weighted row sums of old G (bf16) ----------------
__global__ __launch_bounds__(256) void bias_update_k(
    const u16* __restrict__ Guc, const u16* __restrict__ Glc,
    const float* __restrict__ ucbj, const float* __restrict__ lcbj,
    float* __restrict__ cb_uc, float* __restrict__ cb_lc)
{
    const int gw = blockIdx.x * 4 + (threadIdx.x >> 6);
    const int lane = threadIdx.x & 63;
    const int which = gw >= D;          // 0: uc chain, 1: lc chain
    const int n = which ? gw - D : gw;
    const u16* row = (which ? Glc : Guc) + (size_t)n * D;
    const float* vp = which ? lcbj : ucbj;
    const float* vn = which ? ucbj : lcbj;
    float s = 0.f;
    for (int c2 = 0; c2 < D / 512; ++c2) {
        int base = (c2 * 64 + lane) * 8;
        bf16x8 g8 = *(const bf16x8*)(row + base);
        f32x4 p0 = *(const f32x4*)(vp + base);
        f32x4 p1 = *(const f32x4*)(vp + base + 4);
        f32x4 n0 = *(const f32x4*)(vn + base);
        f32x4 n1 = *(const f32x4*)(vn + base + 4);
#pragma unroll
        for (int e = 0; e < 8; ++e) {
            float g = bf2f((u16)g8[e]);
            float pv = e < 4 ? p0[e] : p1[e - 4];
            float nv = e < 4 ? n0[e] : n1[e - 4];
            s += g * (g > 0.f ? pv : nv);
        }
    }
#pragma unroll
    for (int o = 32; o; o >>= 1) s += __shfl_down(s, o);
    if (lane == 0) {
        float* cb = which ? cb_lc : cb_uc;
        cb[n] += s;
    }
}

// ---------------- GEMM step: out = pos(A)@Bp' + neg(A)@Bn' (B pre-transposed [N][K]) ----------------
__global__ __launch_bounds__(256) void gemm_step(
    const u16* __restrict__ Guc, const u16* __restrict__ Glc,
    const u16* __restrict__ lcsTj, const u16* __restrict__ ucsTj,
    u16* __restrict__ outU, u16* __restrict__ outL)
{
    __shared__ u16 sA[BM * BK];
    __shared__ u16 sBu[BN * BK];
    __shared__ u16 sBl[BN * BK];
    const int chain = blockIdx.z;
    const u16* A  = chain ? Glc : Guc;
    const u16* Bp = chain ? lcsTj : ucsTj;   // multiplies pos(A)
    const u16* Bn = chain ? ucsTj : lcsTj;   // multiplies neg(A)
    u16* out = chain ? outL : outU;
    const int r0 = blockIdx.y * BM, c0 = blockIdx.x * BN;
    const int tid = threadIdx.x, lane = tid & 63, wid = tid >> 6;
    const int mb = (wid >> 1) * 64, nb = (wid & 1) * 64;
    const int lrow = lane & 15, lk = lane >> 4;

    f32x4 acc[4][4] = {};

    for (int kt = 0; kt < D; kt += BK) {
        __syncthreads();
#pragma unroll
        for (int i = 0; i < 2; ++i) {
            int c = tid + i * 256; int row = c >> 2, kc = c & 3;
            int ldsoff = (i * 256 + wid * 64) * 16;
            GLDS(A  + (size_t)(r0 + row) * D + kt + kc * 8, (char*)sA  + ldsoff);
            GLDS(Bp + (size_t)(c0 + row) * D + kt + kc * 8, (char*)sBu + ldsoff);
            GLDS(Bn + (size_t)(c0 + row) * D + kt + kc * 8, (char*)sBl + ldsoff);
        }
        __syncthreads();

        bf16x8 pa[4], na[4], bu[4], bl[4];
#pragma unroll
        for (int mi = 0; mi < 4; ++mi) {
            bf16x8 a = *(const bf16x8*)(sA + (mb + mi * 16 + lrow) * BK + lk * 8);
            splitpn(a, pa[mi], na[mi]);
        }
#pragma unroll
        for (int ni = 0; ni < 4; ++ni) {
            bu[ni] = *(const bf16x8*)(sBu + (nb + ni * 16 + lrow) * BK + lk * 8);
            bl[ni] = *(const bf16x8*)(sBl + (nb + ni * 16 + lrow) * BK + lk * 8);
        }
#pragma unroll
        for (int mi = 0; mi < 4; ++mi)
#pragma unroll
            for (int ni = 0; ni < 4; ++ni) {
                acc[mi][ni] = __builtin_amdgcn_mfma_f32_16x16x32_bf16(pa[mi], bu[ni], acc[mi][ni], 0, 0, 0);
                acc[mi][ni] = __builtin_amdgcn_mfma_f32_16x16x32_bf16(na[mi], bl[ni], acc[mi][ni], 0, 0, 0);
            }
    }

#pragma unroll
    for (int mi = 0; mi < 4; ++mi)
#pragma unroll
        for (int ni = 0; ni < 4; ++ni) {
            int c = c0 + nb + ni * 16 + lrow;
            int rbase = r0 + mb + mi * 16 + lk * 4;
#pragma unroll
            for (int q = 0; q < 4; ++q)
                out[(size_t)(rbase + q) * D + c] = f2bf(acc[mi][ni][q]);
        }
}

// ---------------- final apply to layer-0 bounds, write f32 output ----------------
__global__ __launch_bounds__(256) void final_k(
    const u16* __restrict__ Guc, const u16* __restrict__ Glc,
    const float* __restrict__ cb_uc, const float* __restrict__ cb_lc,
    const float* __restrict__ lb0, const float* __restrict__ ub0,
    float* __restrict__ out)
{
    const int gw = blockIdx.x * 4 + (threadIdx.x >> 6);
    const int lane = threadIdx.x & 63;
    const int which = gw >= D;          // 0: cur_lb (G_lc), 1: cur_ub (G_uc)
    const int n = which ? gw - D : gw;
    const u16* row = (which ? Guc : Glc) + (size_t)n * D;
    const float* vp = which ? ub0 : lb0;
    const float* vn = which ? lb0 : ub0;
    float s = 0.f;
    for (int c2 = 0; c2 < D / 512; ++c2) {
        int base = (c2 * 64 + lane) * 8;
        bf16x8 g8 = *(const bf16x8*)(row + base);
        f32x4 p0 = *(const f32x4*)(vp + base);
        f32x4 p1 = *(const f32x4*)(vp + base + 4);
        f32x4 n0 = *(const f32x4*)(vn + base);
        f32x4 n1 = *(const f32x4*)(vn + base + 4);
#pragma unroll
        for (int e = 0; e < 8; ++e) {
            float g = bf2f((u16)g8[e]);
            float pv = e < 4 ? p0[e] : p1[e - 4];
            float nv = e < 4 ? n0[e] : n1[e - 4];
            s += g * (g > 0.f ? pv : nv);
        }
    }
#pragma unroll
    for (int o = 32; o; o >>= 1) s += __shfl_down(s, o);
    if (lane == 0) {
        float b = (which ? cb_uc : cb_lc)[n];
        out[which * D + n] = s + b;
    }
}

extern "C" void kernel_launch(void* const* d_in, const int* in_sizes, int n_in,
                              void* d_out, int out_size, void* d_ws, size_t ws_size,
                              hipStream_t stream) {
    const float* lb  = (const float*)d_in[0];
    const float* ub  = (const float*)d_in[1];
    const float* lcs = (const float*)d_in[2];
    const float* ucs = (const float*)d_in[3];
    const float* lcb = (const float*)d_in[4];
    const float* ucb = (const float*)d_in[5];
    float* out = (float*)d_out;

    const size_t DD = (size_t)D * D;
    u16* ws   = (u16*)d_ws;
    u16* lcsT = ws;                 // 3*D*D bf16, [N][K] layout
    u16* ucsT = lcsT + 3 * DD;      // 3*D*D bf16
    u16* Ga = ucsT + 3 * DD;        // G ping-pong buffers (bf16)
    u16* Gb = Ga + DD;
    u16* Gc = Gb + DD;
    u16* Gd = Gc + DD;
    float* fbuf  = (float*)(Gd + DD);
    float* lb0   = fbuf;
    float* ub0   = fbuf + D;
    float* cb_uc = fbuf + 2 * D;
    float* cb_lc = fbuf + 3 * D;

    // transpose+convert lcs[0..2], ucs[0..2] into bf16 [N][K] layout
    transpose_k<<<dim3(D / TT, D / TT, 6), 256, 0, stream>>>(lcs, ucs, lcsT, ucsT);
    // convert layer-3 matrices: G_uc = bf16(ucs[3]) -> Ga, G_lc = bf16(lcs[3]) -> Gc
    convert_k<<<dim3(DD / (256 * 8), 2), 256, 0, stream>>>(ucs + 3 * DD, Ga, lcs + 3 * DD, Gc);
    // bias accumulators start at layer-3 biases
    initbias_k<<<dim3(2 * D / 256), 256, 0, stream>>>(ucb + 3 * D, lcb + 3 * D, cb_uc, cb_lc);
    // layer-0 stored bounds (pure f32)
    lb0ub0_k<<<dim3(2 * D / 4), 256, 0, stream>>>(lb, ub, lcs, ucs, lcb, ucb, lb0, ub0);

    u16* curU = Ga; u16* curL = Gc;
    u16* altU = Gb; u16* altL = Gd;
    for (int j = 2; j >= 0; --j) {
        bias_update_k<<<dim3(2 * D / 4), 256, 0, stream>>>(curU, curL, ucb + (size_t)j * D, lcb + (size_t)j * D, cb_uc, cb_lc);
        gemm_step<<<dim3(D / BN, D / BM, 2), 256, 0, stream>>>(curU, curL, lcsT + (size_t)j * DD, ucsT + (size_t)j * DD, altU, altL);
        u16* t;
        t = curU; curU = altU; altU = t;
        t = curL; curL = altL; altL = t;
    }
    final_k<<<dim3(2 * D / 4), 256, 0, stream>>>(curU, curL, cb_uc, cb_lc, lb0, ub0, out);
}

// Round 3
// 167.846 us; speedup vs baseline: 1.3409x; 1.3409x over previous
//
#include <hip/hip_runtime.h>

#define D 1536
#define BT 96          // square output tile
#define BK 32
#define TT 64
#define NCHUNK (3 * BT * BK / 8)   // 16B chunks per K-step stage = 1152

typedef unsigned short u16;
typedef short bf16x8 __attribute__((ext_vector_type(8)));
typedef short short2v __attribute__((ext_vector_type(2)));
typedef float f32x4 __attribute__((ext_vector_type(4)));

static __device__ __forceinline__ float bf2f(u16 s) {
    unsigned u = ((unsigned)s) << 16;
    float f; __builtin_memcpy(&f, &u, 4); return f;
}
static __device__ __forceinline__ u16 f2bf(float f) {
    unsigned u; __builtin_memcpy(&u, &f, 4);
    unsigned r = (u + 0x7FFFu + ((u >> 16) & 1u)) >> 16;
    return (u16)r;
}

// split packed bf16 x8 into positive part and negative part (sign-mask trick)
static __device__ __forceinline__ void splitpn(bf16x8 a, bf16x8& p, bf16x8& n) {
    union U { bf16x8 v; short2v s[4]; unsigned u[4]; } x, up, un;
    x.v = a;
#pragma unroll
    for (int i = 0; i < 4; ++i) {
        short2v m = x.s[i] >> 15;          // v_pk_ashrrev_i16: 0xFFFF where sign set
        unsigned mu; __builtin_memcpy(&mu, &m, 4);
        unsigned ng = x.u[i] & mu;         // keep where negative
        un.u[i] = ng;
        up.u[i] = x.u[i] ^ ng;             // keep where non-negative
    }
    p = up.v; n = un.v;
}

#define GLDS(g, s) __builtin_amdgcn_global_load_lds( \
    (const __attribute__((address_space(1))) void*)(g), \
    (__attribute__((address_space(3))) void*)(s), 16, 0, 0)

// ---------------- transpose+convert: dst_bf16[m][k] = src_f32[k][m], 6 matrices ----------------
__global__ __launch_bounds__(256) void transpose_k(
    const float* __restrict__ lcs, const float* __restrict__ ucs,
    u16* __restrict__ lcsT, u16* __restrict__ ucsT)
{
    __shared__ u16 t[TT][TT + 8];
    const int z = blockIdx.z, j = z >> 1, sel = z & 1;
    const float* src = (sel ? ucs : lcs) + (size_t)j * D * D;
    u16* dst = (sel ? ucsT : lcsT) + (size_t)j * D * D;
    const int r0 = blockIdx.y * TT, c0 = blockIdx.x * TT;
    const int tid = threadIdx.x;
#pragma unroll
    for (int i = 0; i < 2; ++i) {
        int c = tid + i * 256; int r = c >> 3, v = c & 7;
        const float* p = src + (size_t)(r0 + r) * D + c0 + v * 8;
        f32x4 x0 = *(const f32x4*)p;
        f32x4 x1 = *(const f32x4*)(p + 4);
        bf16x8 y;
#pragma unroll
        for (int e = 0; e < 4; ++e) { y[e] = (short)f2bf(x0[e]); y[e + 4] = (short)f2bf(x1[e]); }
        *(bf16x8*)&t[r][v * 8] = y;
    }
    __syncthreads();
#pragma unroll
    for (int i = 0; i < 2; ++i) {
        int c = tid + i * 256; int rr = c >> 3, v = c & 7;
        bf16x8 x;
#pragma unroll
        for (int e = 0; e < 8; ++e) x[e] = (short)t[v * 8 + e][rr];
        *(bf16x8*)(dst + (size_t)(c0 + rr) * D + r0 + v * 8) = x;
    }
}

// ---------------- convert f32 -> bf16 (layer-3 constraint matrices) ----------------
__global__ __launch_bounds__(256) void convert_k(
    const float* __restrict__ src0, u16* __restrict__ dst0,
    const float* __restrict__ src1, u16* __restrict__ dst1)
{
    const float* src = blockIdx.y ? src1 : src0;
    u16* dst = blockIdx.y ? dst1 : dst0;
    size_t i = ((size_t)blockIdx.x * 256 + threadIdx.x) * 8;
    f32x4 x0 = *(const f32x4*)(src + i);
    f32x4 x1 = *(const f32x4*)(src + i + 4);
    bf16x8 y;
#pragma unroll
    for (int e = 0; e < 4; ++e) { y[e] = (short)f2bf(x0[e]); y[e + 4] = (short)f2bf(x1[e]); }
    *(bf16x8*)(dst + i) = y;
}

// ---------------- init bias accumulators (f32) from layer-3 biases ----------------
__global__ __launch_bounds__(256) void initbias_k(
    const float* __restrict__ ucb3, const float* __restrict__ lcb3,
    float* __restrict__ cb_uc, float* __restrict__ cb_lc)
{
    int i = blockIdx.x * 256 + threadIdx.x;
    if (i < D)          cb_uc[i] = ucb3[i];
    else if (i < 2 * D) cb_lc[i - D] = lcb3[i - D];
}

// ---------------- layer-0 forward bounds: one wave per output row (all f32) ----------------
__global__ __launch_bounds__(256) void lb0ub0_k(
    const float* __restrict__ lb, const float* __restrict__ ub,
    const float* __restrict__ lcs0, const float* __restrict__ ucs0,
    const float* __restrict__ lcb0, const float* __restrict__ ucb0,
    float* __restrict__ lb0, float* __restrict__ ub0)
{
    const int gw = blockIdx.x * 4 + (threadIdx.x >> 6);
    const int lane = threadIdx.x & 63;
    const int which = gw >= D;          // 0: lb0 row, 1: ub0 row
    const int n = which ? gw - D : gw;
    const float* row = (which ? ucs0 : lcs0) + (size_t)n * D;
    const float* vp = which ? ub : lb;
    const float* vn = which ? lb : ub;
    float s = 0.f;
    for (int c2 = 0; c2 < D / 256; ++c2) {
        int base = (c2 * 64 + lane) * 4;
        f32x4 g = *(const f32x4*)(row + base);
        f32x4 p = *(const f32x4*)(vp + base);
        f32x4 m = *(const f32x4*)(vn + base);
#pragma unroll
        for (int e = 0; e < 4; ++e) s += g[e] * (g[e] > 0.f ? p[e] : m[e]);
    }
#pragma unroll
    for (int o = 32; o; o >>= 1) s += __shfl_down(s, o);
    if (lane == 0) {
        float b = which ? ucb0[n] : lcb0[n];
        (which ? ub0 : lb0)[n] = s + b;
    }
}

// ---------------- bias recurrence: cb += bias_j-weighted row sums of old G (bf16) ----------------
__global__ __launch_bounds__(256) void bias_update_k(
    const u16* __restrict__ Guc, const u16* __restrict__ Glc,
    const float* __restrict__ ucbj, const float* __restrict__ lcbj,
    float* __restrict__ cb_uc, float* __restrict__ cb_lc)
{
    const int gw = blockIdx.x * 4 + (threadIdx.x >> 6);
    const int lane = threadIdx.x & 63;
    const int which = gw >= D;          // 0: uc chain, 1: lc chain
    const int n = which ? gw - D : gw;
    const u16* row = (which ? Glc : Guc) + (size_t)n * D;
    const float* vp = which ? lcbj : ucbj;
    const float* vn = which ? ucbj : lcbj;
    float s = 0.f;
    for (int c2 = 0; c2 < D / 512; ++c2) {
        int base = (c2 * 64 + lane) * 8;
        bf16x8 g8 = *(const bf16x8*)(row + base);
        f32x4 p0 = *(const f32x4*)(vp + base);
        f32x4 p1 = *(const f32x4*)(vp + base + 4);
        f32x4 n0 = *(const f32x4*)(vn + base);
        f32x4 n1 = *(const f32x4*)(vn + base + 4);
#pragma unroll
        for (int e = 0; e < 8; ++e) {
            float g = bf2f((u16)g8[e]);
            float pv = e < 4 ? p0[e] : p1[e - 4];
            float nv = e < 4 ? n0[e] : n1[e - 4];
            s += g * (g > 0.f ? pv : nv);
        }
    }
#pragma unroll
    for (int o = 32; o; o >>= 1) s += __shfl_down(s, o);
    if (lane == 0) {
        float* cb = which ? cb_lc : cb_uc;
        cb[n] += s;
    }
}

// ---------------- GEMM step: out = pos(A)@Bp' + neg(A)@Bn' (B pre-transposed [N][K]) ----------------
// 96x96 tile, 4 waves (2x2), per-wave 48x48. LDS XOR-swizzled via pre-swizzled
// global source (global_load_lds writes linearly; rule #21).
__global__ __launch_bounds__(256, 2) void gemm_step(
    const u16* __restrict__ Guc, const u16* __restrict__ Glc,
    const u16* __restrict__ lcsTj, const u16* __restrict__ ucsTj,
    u16* __restrict__ outU, u16* __restrict__ outL)
{
    __shared__ u16 smem[3 * BT * BK];       // sA | sBu | sBl
    const int chain = blockIdx.z;
    const u16* A  = chain ? Glc : Guc;
    const u16* Bp = chain ? lcsTj : ucsTj;   // multiplies pos(A)
    const u16* Bn = chain ? ucsTj : lcsTj;   // multiplies neg(A)
    u16* out = chain ? outL : outU;
    const int r0 = blockIdx.y * BT, c0 = blockIdx.x * BT;
    const int tid = threadIdx.x, lane = tid & 63, wid = tid >> 6;
    const int mb = (wid >> 1) * 48, nb = (wid & 1) * 48;
    const int lrow = lane & 15, lk = lane >> 4;

    f32x4 acc[3][3] = {};

    for (int kt = 0; kt < D; kt += BK) {
        __syncthreads();
        // stage NCHUNK=1152 chunks of 16B: chunk c -> buffer c/384, row (c%384)>>2, kslot c&3
        // stored with pre-swizzled global k-slot: kcg = kc ^ (row&3) ^ ((row>>2)&3)
#pragma unroll
        for (int i = 0; i < 5; ++i) {
            int c = i * 256 + tid;
            if (c < NCHUNK) {
                int b = c / 384;
                int idx = c - b * 384;
                int row = idx >> 2, kc = idx & 3;
                int kcg = kc ^ (row & 3) ^ ((row >> 2) & 3);
                const u16* base = (b == 0) ? (A + (size_t)(r0 + row) * D)
                                           : ((b == 1 ? Bp : Bn) + (size_t)(c0 + row) * D);
                GLDS(base + kt + kcg * 8, (char*)smem + (i * 256 + wid * 64) * 16);
            }
        }
        __syncthreads();

        bf16x8 pa[3], na[3], bu[3], bl[3];
#pragma unroll
        for (int mi = 0; mi < 3; ++mi) {
            int row = mb + mi * 16 + lrow;
            int x = lk ^ (row & 3) ^ ((row >> 2) & 3);
            bf16x8 a = *(const bf16x8*)(smem + row * BK + x * 8);
            splitpn(a, pa[mi], na[mi]);
        }
#pragma unroll
        for (int ni = 0; ni < 3; ++ni) {
            int row = nb + ni * 16 + lrow;
            int x = lk ^ (row & 3) ^ ((row >> 2) & 3);
            bu[ni] = *(const bf16x8*)(smem + BT * BK + row * BK + x * 8);
            bl[ni] = *(const bf16x8*)(smem + 2 * BT * BK + row * BK + x * 8);
        }
#pragma unroll
        for (int mi = 0; mi < 3; ++mi)
#pragma unroll
            for (int ni = 0; ni < 3; ++ni) {
                acc[mi][ni] = __builtin_amdgcn_mfma_f32_16x16x32_bf16(pa[mi], bu[ni], acc[mi][ni], 0, 0, 0);
                acc[mi][ni] = __builtin_amdgcn_mfma_f32_16x16x32_bf16(na[mi], bl[ni], acc[mi][ni], 0, 0, 0);
            }
    }

#pragma unroll
    for (int mi = 0; mi < 3; ++mi)
#pragma unroll
        for (int ni = 0; ni < 3; ++ni) {
            int c = c0 + nb + ni * 16 + lrow;
            int rbase = r0 + mb + mi * 16 + lk * 4;
#pragma unroll
            for (int q = 0; q < 4; ++q)
                out[(size_t)(rbase + q) * D + c] = f2bf(acc[mi][ni][q]);
        }
}

// ---------------- final apply to layer-0 bounds, write f32 output ----------------
__global__ __launch_bounds__(256) void final_k(
    const u16* __restrict__ Guc, const u16* __restrict__ Glc,
    const float* __restrict__ cb_uc, const float* __restrict__ cb_lc,
    const float* __restrict__ lb0, const float* __restrict__ ub0,
    float* __restrict__ out)
{
    const int gw = blockIdx.x * 4 + (threadIdx.x >> 6);
    const int lane = threadIdx.x & 63;
    const int which = gw >= D;          // 0: cur_lb (G_lc), 1: cur_ub (G_uc)
    const int n = which ? gw - D : gw;
    const u16* row = (which ? Guc : Glc) + (size_t)n * D;
    const float* vp = which ? ub0 : lb0;
    const float* vn = which ? lb0 : ub0;
    float s = 0.f;
    for (int c2 = 0; c2 < D / 512; ++c2) {
        int base = (c2 * 64 + lane) * 8;
        bf16x8 g8 = *(const bf16x8*)(row + base);
        f32x4 p0 = *(const f32x4*)(vp + base);
        f32x4 p1 = *(const f32x4*)(vp + base + 4);
        f32x4 n0 = *(const f32x4*)(vn + base);
        f32x4 n1 = *(const f32x4*)(vn + base + 4);
#pragma unroll
        for (int e = 0; e < 8; ++e) {
            float g = bf2f((u16)g8[e]);
            float pv = e < 4 ? p0[e] : p1[e - 4];
            float nv = e < 4 ? n0[e] : n1[e - 4];
            s += g * (g > 0.f ? pv : nv);
        }
    }
#pragma unroll
    for (int o = 32; o; o >>= 1) s += __shfl_down(s, o);
    if (lane == 0) {
        float b = (which ? cb_uc : cb_lc)[n];
        out[which * D + n] = s + b;
    }
}

extern "C" void kernel_launch(void* const* d_in, const int* in_sizes, int n_in,
                              void* d_out, int out_size, void* d_ws, size_t ws_size,
                              hipStream_t stream) {
    const float* lb  = (const float*)d_in[0];
    const float* ub  = (const float*)d_in[1];
    const float* lcs = (const float*)d_in[2];
    const float* ucs = (const float*)d_in[3];
    const float* lcb = (const float*)d_in[4];
    const float* ucb = (const float*)d_in[5];
    float* out = (float*)d_out;

    const size_t DD = (size_t)D * D;
    u16* ws   = (u16*)d_ws;
    u16* lcsT = ws;                 // 3*D*D bf16, [N][K] layout
    u16* ucsT = lcsT + 3 * DD;      // 3*D*D bf16
    u16* Ga = ucsT + 3 * DD;        // G ping-pong buffers (bf16)
    u16* Gb = Ga + DD;
    u16* Gc = Gb + DD;
    u16* Gd = Gc + DD;
    float* fbuf  = (float*)(Gd + DD);
    float* lb0   = fbuf;
    float* ub0   = fbuf + D;
    float* cb_uc = fbuf + 2 * D;
    float* cb_lc = fbuf + 3 * D;

    // transpose+convert lcs[0..2], ucs[0..2] into bf16 [N][K] layout
    transpose_k<<<dim3(D / TT, D / TT, 6), 256, 0, stream>>>(lcs, ucs, lcsT, ucsT);
    // convert layer-3 matrices: G_uc = bf16(ucs[3]) -> Ga, G_lc = bf16(lcs[3]) -> Gc
    convert_k<<<dim3(DD / (256 * 8), 2), 256, 0, stream>>>(ucs + 3 * DD, Ga, lcs + 3 * DD, Gc);
    // bias accumulators start at layer-3 biases
    initbias_k<<<dim3(2 * D / 256), 256, 0, stream>>>(ucb + 3 * D, lcb + 3 * D, cb_uc, cb_lc);
    // layer-0 stored bounds (pure f32)
    lb0ub0_k<<<dim3(2 * D / 4), 256, 0, stream>>>(lb, ub, lcs, ucs, lcb, ucb, lb0, ub0);

    u16* curU = Ga; u16* curL = Gc;
    u16* altU = Gb; u16* altL = Gd;
    for (int j = 2; j >= 0; --j) {
        bias_update_k<<<dim3(2 * D / 4), 256, 0, stream>>>(curU, curL, ucb + (size_t)j * D, lcb + (size_t)j * D, cb_uc, cb_lc);
        gemm_step<<<dim3(D / BT, D / BT, 2), 256, 0, stream>>>(curU, curL, lcsT + (size_t)j * DD, ucsT + (size_t)j * DD, altU, altL);
        u16* t;
        t = curU; curU = altU; altU = t;
        t = curL; curL = altL; altL = t;
    }
    final_k<<<dim3(2 * D / 4), 256, 0, stream>>>(curU, curL, cb_uc, cb_lc, lb0, ub0, out);
}

// Round 4
// 134.159 us; speedup vs baseline: 1.6776x; 1.2511x over previous
//
#include <hip/hip_runtime.h>

#define D 1536
#define BT 96          // square output tile
#define BK 64          // K-step
#define NT (D / BK)    // 24 K-steps
#define TT 64

typedef unsigned short u16;
typedef short bf16x8 __attribute__((ext_vector_type(8)));
typedef short short2v __attribute__((ext_vector_type(2)));
typedef float f32x4 __attribute__((ext_vector_type(4)));

static __device__ __forceinline__ float bf2f(u16 s) {
    unsigned u = ((unsigned)s) << 16;
    float f; __builtin_memcpy(&f, &u, 4); return f;
}
static __device__ __forceinline__ u16 f2bf(float f) {
    unsigned u; __builtin_memcpy(&u, &f, 4);
    unsigned r = (u + 0x7FFFu + ((u >> 16) & 1u)) >> 16;
    return (u16)r;
}

// split packed bf16 x8 into positive part and negative part (sign-mask trick)
static __device__ __forceinline__ void splitpn(bf16x8 a, bf16x8& p, bf16x8& n) {
    union U { bf16x8 v; short2v s[4]; unsigned u[4]; } x, up, un;
    x.v = a;
#pragma unroll
    for (int i = 0; i < 4; ++i) {
        short2v m = x.s[i] >> 15;          // 0xFFFF where sign set
        unsigned mu; __builtin_memcpy(&mu, &m, 4);
        unsigned ng = x.u[i] & mu;         // keep where negative
        un.u[i] = ng;
        up.u[i] = x.u[i] ^ ng;             // keep where non-negative
    }
    p = up.v; n = un.v;
}

#define GLDS(g, s) __builtin_amdgcn_global_load_lds( \
    (const __attribute__((address_space(1))) void*)(g), \
    (__attribute__((address_space(3))) void*)(s), 16, 0, 0)

// ---------------- prep: z=0..5 transpose+convert lcs/ucs[0..2]; z=6,7 convert layer-3 ----------------
__global__ __launch_bounds__(256) void prep_k(
    const float* __restrict__ lcs, const float* __restrict__ ucs,
    u16* __restrict__ lcsT, u16* __restrict__ ucsT,
    u16* __restrict__ Ga, u16* __restrict__ Gc)
{
    const int z = blockIdx.z;
    const int r0 = blockIdx.y * TT, c0 = blockIdx.x * TT;
    const int tid = threadIdx.x;

    if (z >= 6) {  // straight convert: ucs[3]->Ga (z=6), lcs[3]->Gc (z=7)
        const float* src = (z == 6 ? ucs : lcs) + (size_t)3 * D * D;
        u16* dst = (z == 6) ? Ga : Gc;
#pragma unroll
        for (int i = 0; i < 2; ++i) {
            int r = (tid >> 3) + i * 32, cc = (tid & 7) * 8;
            const float* p = src + (size_t)(r0 + r) * D + c0 + cc;
            f32x4 x0 = *(const f32x4*)p;
            f32x4 x1 = *(const f32x4*)(p + 4);
            bf16x8 y;
#pragma unroll
            for (int e = 0; e < 4; ++e) { y[e] = (short)f2bf(x0[e]); y[e + 4] = (short)f2bf(x1[e]); }
            *(bf16x8*)(dst + (size_t)(r0 + r) * D + c0 + cc) = y;
        }
        return;
    }

    __shared__ u16 t[TT][TT + 8];
    const int j = z >> 1, sel = z & 1;
    const float* src = (sel ? ucs : lcs) + (size_t)j * D * D;
    u16* dst = (sel ? ucsT : lcsT) + (size_t)j * D * D;
#pragma unroll
    for (int i = 0; i < 2; ++i) {
        int c = tid + i * 256; int r = c >> 3, v = c & 7;
        const float* p = src + (size_t)(r0 + r) * D + c0 + v * 8;
        f32x4 x0 = *(const f32x4*)p;
        f32x4 x1 = *(const f32x4*)(p + 4);
        bf16x8 y;
#pragma unroll
        for (int e = 0; e < 4; ++e) { y[e] = (short)f2bf(x0[e]); y[e + 4] = (short)f2bf(x1[e]); }
        *(bf16x8*)&t[r][v * 8] = y;
    }
    __syncthreads();
#pragma unroll
    for (int i = 0; i < 2; ++i) {
        int c = tid + i * 256; int rr = c >> 3, v = c & 7;
        bf16x8 x;
#pragma unroll
        for (int e = 0; e < 8; ++e) x[e] = (short)t[v * 8 + e][rr];
        *(bf16x8*)(dst + (size_t)(c0 + rr) * D + r0 + v * 8) = x;
    }
}

// ---------------- vec: lb0/ub0 rows + cb init (layer-3 bias + j=2 bias update), all f32 ----------------
__global__ __launch_bounds__(256) void vec_k(
    const float* __restrict__ lb, const float* __restrict__ ub,
    const float* __restrict__ lcs, const float* __restrict__ ucs,
    const float* __restrict__ lcb, const float* __restrict__ ucb,
    float* __restrict__ lb0, float* __restrict__ ub0,
    float* __restrict__ cb_uc, float* __restrict__ cb_lc)
{
    const int tt = blockIdx.x * 4 + (threadIdx.x >> 6);
    const int lane = threadIdx.x & 63;
    const int kind = tt >> 10;          // /1024? no: tt / 1536
    const int n = tt & 1535;            // D = 1536 = 3*512, careful: use explicit
    const int which = tt / D;           // 0:lb0 1:ub0 2:cb_uc 3:cb_lc
    const int row_n = tt - which * D;

    const float* row; const float* vp; const float* vn;
    if (which == 0)      { row = lcs + (size_t)row_n * D;               vp = lb;           vn = ub; }
    else if (which == 1) { row = ucs + (size_t)row_n * D;               vp = ub;           vn = lb; }
    else if (which == 2) { row = ucs + (size_t)(3 * (size_t)D * D) + (size_t)row_n * D; vp = ucb + 2 * D; vn = lcb + 2 * D; }
    else                 { row = lcs + (size_t)(3 * (size_t)D * D) + (size_t)row_n * D; vp = lcb + 2 * D; vn = ucb + 2 * D; }

    float s = 0.f;
    for (int c2 = 0; c2 < D / 256; ++c2) {
        int base = (c2 * 64 + lane) * 4;
        f32x4 g = *(const f32x4*)(row + base);
        f32x4 p = *(const f32x4*)(vp + base);
        f32x4 m = *(const f32x4*)(vn + base);
#pragma unroll
        for (int e = 0; e < 4; ++e) s += g[e] * (g[e] > 0.f ? p[e] : m[e]);
    }
#pragma unroll
    for (int o = 32; o; o >>= 1) s += __shfl_down(s, o);
    if (lane == 0) {
        if (which == 0)      lb0[row_n] = s + lcb[row_n];
        else if (which == 1) ub0[row_n] = s + ucb[row_n];
        else if (which == 2) cb_uc[row_n] = s + ucb[3 * D + row_n];
        else                 cb_lc[row_n] = s + lcb[3 * D + row_n];
    }
    (void)kind; (void)n;
}

// ---------------- GEMM step: out = pos(A)@Bp' + neg(A)@Bn', pipelined double-buffer ----------------
// 96x96 tile, BK=64, 4 waves (2x2), per-wave 48x48. LDS XOR-swizzle slot^(row&7)
// via pre-swizzled global source (global_load_lds writes linearly; rule #21).
// Fused epilogue: bias recurrence for the NEXT backsub step from f32 accumulators.
struct GemmArgs { };

static __device__ __forceinline__ void stage_tile(
    const u16* __restrict__ A, const u16* __restrict__ Bp, const u16* __restrict__ Bn,
    int r0, int c0, int kt, u16* __restrict__ sbuf, int tid, int wid)
{
#pragma unroll
    for (int i = 0; i < 9; ++i) {
        const int idx = (i % 3) * 256 + tid;
        const int row = idx >> 3;                // 0..95
        const int kc = tid & 7;
        const int kcg = kc ^ (row & 7);          // pre-swizzled global k-slot
        const u16* base = (i < 3) ? (A + (size_t)(r0 + row) * D)
                        : ((i < 6) ? (Bp + (size_t)(c0 + row) * D)
                                   : (Bn + (size_t)(c0 + row) * D));
        GLDS(base + kt + kcg * 8, (char*)sbuf + (i * 256 + wid * 64) * 16);
    }
}

static __device__ __forceinline__ void compute_tile(
    const u16* __restrict__ sbuf, f32x4 (&acc)[3][3], int mb, int nb, int lrow, int lk)
{
#pragma unroll
    for (int ks = 0; ks < 2; ++ks) {
        const int slot = ks * 4 + lk;
        bf16x8 pa[3], na[3];
#pragma unroll
        for (int mi = 0; mi < 3; ++mi) {
            int row = mb + mi * 16 + lrow;
            int x = slot ^ (row & 7);
            bf16x8 a = *(const bf16x8*)(sbuf + row * BK + x * 8);
            splitpn(a, pa[mi], na[mi]);
        }
#pragma unroll
        for (int ni = 0; ni < 3; ++ni) {
            int row = nb + ni * 16 + lrow;
            int x = slot ^ (row & 7);
            bf16x8 bu = *(const bf16x8*)(sbuf + BT * BK + row * BK + x * 8);
            bf16x8 bl = *(const bf16x8*)(sbuf + 2 * BT * BK + row * BK + x * 8);
#pragma unroll
            for (int mi = 0; mi < 3; ++mi) {
                acc[mi][ni] = __builtin_amdgcn_mfma_f32_16x16x32_bf16(pa[mi], bu, acc[mi][ni], 0, 0, 0);
                acc[mi][ni] = __builtin_amdgcn_mfma_f32_16x16x32_bf16(na[mi], bl, acc[mi][ni], 0, 0, 0);
            }
        }
    }
}

__global__ __launch_bounds__(256, 2) void gemm_step(
    const u16* __restrict__ Guc, const u16* __restrict__ Glc,
    const u16* __restrict__ lcsTj, const u16* __restrict__ ucsTj,
    u16* __restrict__ outU, u16* __restrict__ outL,
    const float* __restrict__ ucbN, const float* __restrict__ lcbN,
    float* __restrict__ cb_uc, float* __restrict__ cb_lc)
{
    __shared__ u16 smemA[3 * BT * BK];
    __shared__ u16 smemB[3 * BT * BK];
    const int chain = blockIdx.z;
    const u16* A  = chain ? Glc : Guc;
    const u16* Bp = chain ? lcsTj : ucsTj;   // multiplies pos(A)
    const u16* Bn = chain ? ucsTj : lcsTj;   // multiplies neg(A)
    u16* out = chain ? outL : outU;
    const int r0 = blockIdx.y * BT, c0 = blockIdx.x * BT;
    const int tid = threadIdx.x, lane = tid & 63, wid = tid >> 6;
    const int mb = (wid >> 1) * 48, nb = (wid & 1) * 48;
    const int lrow = lane & 15, lk = lane >> 4;

    f32x4 acc[3][3] = {};

    // prologue: fill buffer A
    stage_tile(A, Bp, Bn, r0, c0, 0, smemA, tid, wid);
    asm volatile("s_waitcnt vmcnt(0)" ::: "memory");
    __syncthreads();

    // pipelined main loop: stage(next) || compute(cur); one barrier per K-step
#pragma unroll 1
    for (int t2 = 0; t2 < NT / 2; ++t2) {
        const int t = t2 * 2;
        stage_tile(A, Bp, Bn, r0, c0, (t + 1) * BK, smemB, tid, wid);
        compute_tile(smemA, acc, mb, nb, lrow, lk);
        __syncthreads();                  // drains vmcnt -> smemB ready
        if (t2 < NT / 2 - 1)
            stage_tile(A, Bp, Bn, r0, c0, (t + 2) * BK, smemA, tid, wid);
        compute_tile(smemB, acc, mb, nb, lrow, lk);
        __syncthreads();                  // drains vmcnt -> smemA ready
    }

    // fused bias recurrence for next backsub step (from f32 accumulators)
    if (ucbN) {
        const float* pb_ = chain ? lcbN : ucbN;
        const float* nb_ = chain ? ucbN : lcbN;
        float* cb = chain ? cb_lc : cb_uc;
        float pbv[3], nbv[3];
#pragma unroll
        for (int ni = 0; ni < 3; ++ni) {
            int c = c0 + nb + ni * 16 + lrow;
            pbv[ni] = pb_[c]; nbv[ni] = nb_[c];
        }
#pragma unroll
        for (int mi = 0; mi < 3; ++mi)
#pragma unroll
            for (int q = 0; q < 4; ++q) {
                float s = 0.f;
#pragma unroll
                for (int ni = 0; ni < 3; ++ni) {
                    float g = acc[mi][ni][q];
                    s += g * (g > 0.f ? pbv[ni] : nbv[ni]);
                }
                s += __shfl_xor(s, 1); s += __shfl_xor(s, 2);
                s += __shfl_xor(s, 4); s += __shfl_xor(s, 8);
                if (lrow == 0)
                    atomicAdd(&cb[r0 + mb + mi * 16 + lk * 4 + q], s);
            }
    }

#pragma unroll
    for (int mi = 0; mi < 3; ++mi)
#pragma unroll
        for (int ni = 0; ni < 3; ++ni) {
            int c = c0 + nb + ni * 16 + lrow;
            int rbase = r0 + mb + mi * 16 + lk * 4;
#pragma unroll
            for (int q = 0; q < 4; ++q)
                out[(size_t)(rbase + q) * D + c] = f2bf(acc[mi][ni][q]);
        }
}

// ---------------- final apply to layer-0 bounds, write f32 output ----------------
__global__ __launch_bounds__(256) void final_k(
    const u16* __restrict__ Guc, const u16* __restrict__ Glc,
    const float* __restrict__ cb_uc, const float* __restrict__ cb_lc,
    const float* __restrict__ lb0, const float* __restrict__ ub0,
    float* __restrict__ out)
{
    const int gw = blockIdx.x * 4 + (threadIdx.x >> 6);
    const int lane = threadIdx.x & 63;
    const int which = gw >= D;          // 0: cur_lb (G_lc), 1: cur_ub (G_uc)
    const int n = which ? gw - D : gw;
    const u16* row = (which ? Guc : Glc) + (size_t)n * D;
    const float* vp = which ? ub0 : lb0;
    const float* vn = which ? lb0 : ub0;
    float s = 0.f;
    for (int c2 = 0; c2 < D / 512; ++c2) {
        int base = (c2 * 64 + lane) * 8;
        bf16x8 g8 = *(const bf16x8*)(row + base);
        f32x4 p0 = *(const f32x4*)(vp + base);
        f32x4 p1 = *(const f32x4*)(vp + base + 4);
        f32x4 n0 = *(const f32x4*)(vn + base);
        f32x4 n1 = *(const f32x4*)(vn + base + 4);
#pragma unroll
        for (int e = 0; e < 8; ++e) {
            float g = bf2f((u16)g8[e]);
            float pv = e < 4 ? p0[e] : p1[e - 4];
            float nv = e < 4 ? n0[e] : n1[e - 4];
            s += g * (g > 0.f ? pv : nv);
        }
    }
#pragma unroll
    for (int o = 32; o; o >>= 1) s += __shfl_down(s, o);
    if (lane == 0) {
        float b = (which ? cb_uc : cb_lc)[n];
        out[which * D + n] = s + b;
    }
}

extern "C" void kernel_launch(void* const* d_in, const int* in_sizes, int n_in,
                              void* d_out, int out_size, void* d_ws, size_t ws_size,
                              hipStream_t stream) {
    const float* lb  = (const float*)d_in[0];
    const float* ub  = (const float*)d_in[1];
    const float* lcs = (const float*)d_in[2];
    const float* ucs = (const float*)d_in[3];
    const float* lcb = (const float*)d_in[4];
    const float* ucb = (const float*)d_in[5];
    float* out = (float*)d_out;

    const size_t DD = (size_t)D * D;
    u16* ws   = (u16*)d_ws;
    u16* lcsT = ws;                 // 3*D*D bf16, [N][K] layout
    u16* ucsT = lcsT + 3 * DD;      // 3*D*D bf16
    u16* Ga = ucsT + 3 * DD;        // G ping-pong buffers (bf16)
    u16* Gb = Ga + DD;
    u16* Gc = Gb + DD;
    u16* Gd = Gc + DD;
    float* fbuf  = (float*)(Gd + DD);
    float* lb0   = fbuf;
    float* ub0   = fbuf + D;
    float* cb_uc = fbuf + 2 * D;
    float* cb_lc = fbuf + 3 * D;

    // transposes + layer-3 converts in one launch
    prep_k<<<dim3(D / TT, D / TT, 8), 256, 0, stream>>>(lcs, ucs, lcsT, ucsT, Ga, Gc);
    // lb0/ub0 + cb init (layer-3 bias + j=2 bias update), pure f32
    vec_k<<<dim3(4 * D / 4), 256, 0, stream>>>(lb, ub, lcs, ucs, lcb, ucb, lb0, ub0, cb_uc, cb_lc);

    u16* curU = Ga; u16* curL = Gc;
    u16* altU = Gb; u16* altL = Gd;
    for (int j = 2; j >= 0; --j) {
        const float* ucbN = (j > 0) ? (ucb + (size_t)(j - 1) * D) : nullptr;
        const float* lcbN = (j > 0) ? (lcb + (size_t)(j - 1) * D) : nullptr;
        gemm_step<<<dim3(D / BT, D / BT, 2), 256, 0, stream>>>(
            curU, curL, lcsT + (size_t)j * DD, ucsT + (size_t)j * DD, altU, altL,
            ucbN, lcbN, cb_uc, cb_lc);
        u16* t;
        t = curU; curU = altU; altU = t;
        t = curL; curL = altL; altL = t;
    }
    final_k<<<dim3(2 * D / 4), 256, 0, stream>>>(curU, curL, cb_uc, cb_lc, lb0, ub0, out);
}